// Round 13
// baseline (681.052 us; speedup 1.0000x reference)
//
#include <hip/hip_runtime.h>
#include <math.h>

#define NN 100000
#define FIN 27
#define EMB 64
#define HH 128
#define LAYERS 4
#define GG 512
#define SCAN_CHUNK 2048   // 256 threads x 8 elements
#define SPAN 512          // nodes per bucket
#define SPANSHIFT 9
#define MAXNB 256
#define ECAP 16384        // per-bucket edge slab capacity (mean ~8163)
#define LPAD_US 136       // LDS row stride in ushorts: 272B, 16B-aligned rows

typedef __attribute__((ext_vector_type(8))) short short8;
typedef __attribute__((ext_vector_type(4))) float floatx4;

__device__ __forceinline__ float sigmf(float x) { return 1.0f / (1.0f + __expf(-x)); }
__device__ __forceinline__ float tanhfast(float x) { return 1.0f - 2.0f / (__expf(2.0f * x) + 1.0f); }

__device__ __forceinline__ unsigned short f2bf(float f) {
    unsigned int u = __float_as_uint(f);
    u += 0x7FFFu + ((u >> 16) & 1u);
    return (unsigned short)(u >> 16);
}

__device__ __forceinline__ float bflo(unsigned int v) { return __uint_as_float(v << 16); }
__device__ __forceinline__ float bfhi(unsigned int v) { return __uint_as_float(v & 0xFFFF0000u); }
__device__ __forceinline__ float bfs(unsigned short v) { return __uint_as_float(((unsigned)v) << 16); }

// x1 = sigmoid(x @ lin0_w) (fp32, exact output); h = pad(x1) to 128, bf16 only.
__global__ void lin0_kernel(const float* __restrict__ x, const float* __restrict__ w,
                            float* __restrict__ x1_out, unsigned short* __restrict__ hbf, int n) {
    int wave = (int)((blockIdx.x * blockDim.x + threadIdx.x) >> 6);
    int lane = threadIdx.x & 63;
    if (wave >= n) return;
    const float* xr = x + (size_t)wave * FIN;
    float acc = 0.0f;
#pragma unroll
    for (int k = 0; k < FIN; ++k) acc += xr[k] * w[k * EMB + lane];
    float v = 1.0f / (1.0f + expf(-acc));
    x1_out[(size_t)wave * EMB + lane] = v;
    size_t base = (size_t)wave * HH;
    hbf[base + lane] = f2bf(v);
    hbf[base + 64 + lane] = 0;
}

// Direct-reservation bucketed scatter: one pass over edges. Per-block LDS hist,
// one global atomic per (block,bucket), packed (dst_local<<17)|src into slab b*ECAP.
__global__ void bucket_scatter_direct(const int* __restrict__ src, const int* __restrict__ dst,
                                      int* __restrict__ bucket_cnt, unsigned* __restrict__ ebuf,
                                      int e) {
    __shared__ int lh[MAXNB];
    __shared__ int gb[MAXNB];
    int t = threadIdx.x;  // 1024
    for (int i = t; i < MAXNB; i += 1024) lh[i] = 0;
    __syncthreads();
    int base = blockIdx.x * 16384;
    int lidx[16], sv[16], dv[16];
#pragma unroll
    for (int i = 0; i < 16; ++i) {
        int eid = base + i * 1024 + t;
        if (eid < e) {
            sv[i] = src[eid];
            dv[i] = dst[eid];
            lidx[i] = atomicAdd(&lh[dv[i] >> SPANSHIFT], 1);
        } else lidx[i] = -1;
    }
    __syncthreads();
    for (int i = t; i < MAXNB; i += 1024) {
        int c = lh[i];
        gb[i] = c ? atomicAdd(&bucket_cnt[i], c) : 0;
    }
    __syncthreads();
#pragma unroll
    for (int i = 0; i < 16; ++i) {
        if (lidx[i] >= 0) {
            int b = dv[i] >> SPANSHIFT;
            int pos = gb[b] + lidx[i];
            if (pos < ECAP) {
                unsigned dl = (unsigned)(dv[i] - (b << SPANSHIFT));
                ebuf[(size_t)b * ECAP + pos] = (dl << 17) | (unsigned)sv[i];
            }
        }
    }
}

// Per-node degree via per-bucket LDS histogram.
__global__ void deg_from_buckets(const unsigned* __restrict__ ebuf, const int* __restrict__ bucket_cnt,
                                 int* __restrict__ deg, int n) {
    __shared__ int ld[SPAN];
    int b = blockIdx.x, t = threadIdx.x;  // 256
    ld[t] = 0; ld[t + 256] = 0;
    __syncthreads();
    int cnt = bucket_cnt[b];
    if (cnt > ECAP) cnt = ECAP;
    size_t base = (size_t)b * ECAP;
    int nodebase = b << SPANSHIFT;
    for (int j = t; j < cnt; j += 256)
        atomicAdd(&ld[ebuf[base + j] >> 17], 1);
    __syncthreads();
    int i0 = nodebase + t, i1 = nodebase + 256 + t;
    if (i0 < n) deg[i0] = ld[t];
    if (i1 < n) deg[i1] = ld[t + 256];
}

// ---- multi-block exclusive scan of deg -> rowptr ----
__global__ void scan_partial(const int* __restrict__ deg, int* __restrict__ blocksum, int n) {
    int b = blockIdx.x, t = threadIdx.x;
    int base = b * SCAN_CHUNK + t * 8;
    int s = 0;
#pragma unroll
    for (int i = 0; i < 8; ++i) {
        int idx = base + i;
        if (idx < n) s += deg[idx];
    }
#pragma unroll
    for (int off = 32; off > 0; off >>= 1) s += __shfl_down(s, off, 64);
    __shared__ int ws[4];
    if ((t & 63) == 0) ws[t >> 6] = s;
    __syncthreads();
    if (t == 0) blocksum[b] = ws[0] + ws[1] + ws[2] + ws[3];
}

__global__ void scan_blocksums(const int* __restrict__ blocksum, int* __restrict__ blockoff, int nb) {
    int t = threadIdx.x;
    int own = (t < nb) ? blocksum[t] : 0;
    int v = own;
    for (int off = 1; off < 64; off <<= 1) {
        int u = __shfl_up(v, off, 64);
        if (t >= off) v += u;
    }
    if (t < nb) blockoff[t] = v - own;
}

__global__ void scan_final(const int* __restrict__ deg, const int* __restrict__ blockoff,
                           int* __restrict__ rowptr, int n) {
    int b = blockIdx.x, t = threadIdx.x;
    int base = b * SCAN_CHUNK + t * 8;
    int v[8];
    int s = 0;
#pragma unroll
    for (int i = 0; i < 8; ++i) {
        int idx = base + i;
        v[i] = (idx < n) ? deg[idx] : 0;
        s += v[i];
    }
    __shared__ int ts[256];
    ts[t] = s;
    __syncthreads();
    for (int off = 1; off < 256; off <<= 1) {
        int u = (t >= off) ? ts[t - off] : 0;
        __syncthreads();
        ts[t] += u;
        __syncthreads();
    }
    int run = blockoff[b] + ((t == 0) ? 0 : ts[t - 1]);
#pragma unroll
    for (int i = 0; i < 8; ++i) {
        int idx = base + i;
        if (idx < n) {
            rowptr[idx] = run;
            run += v[i];
        } else if (idx == n) {
            rowptr[n] = run;
        }
    }
}

// Place edges into CSR col with LDS cursors; writes confined to ~32KB/bucket.
__global__ void place_kernel(const unsigned* __restrict__ ebuf, const int* __restrict__ bucket_cnt,
                             const int* __restrict__ rowptr, int* __restrict__ col, int n) {
    __shared__ int cur[SPAN];
    int b = blockIdx.x, t = threadIdx.x;  // 256
    int nodebase = b << SPANSHIFT;
    int i0 = nodebase + t, i1 = nodebase + 256 + t;
    cur[t] = (i0 < n) ? rowptr[i0] : 0;
    cur[t + 256] = (i1 < n) ? rowptr[i1] : 0;
    __syncthreads();
    int cnt = bucket_cnt[b];
    if (cnt > ECAP) cnt = ECAP;
    size_t base = (size_t)b * ECAP;
    for (int j = t; j < cnt; j += 256) {
        unsigned ed = ebuf[base + j];
        int pos = atomicAdd(&cur[ed >> 17], 1);
        col[pos] = (int)(ed & 0x1FFFFu);
    }
}

// Pack whh^T into MFMA B-fragment order.
__global__ void pack_whh(const float* __restrict__ w_hh, unsigned short* __restrict__ whhp) {
    int id = blockIdx.x * blockDim.x + threadIdx.x;
    if (id >= 4 * 24 * 64 * 8) return;
    int j = id & 7;
    int lane = (id >> 3) & 63;
    int ctkt = id >> 9;
    int ct = ctkt % 24;
    int kt = ctkt / 24;
    int k = kt * 32 + (lane >> 4) * 8 + j;
    int col = ct * 16 + (lane & 15);
    whhp[id] = f2bf(w_hh[col * HH + k]);
}

// Wf[l] = ggc[l] @ w_ih^T, packed in MFMA B-fragment order (bf16).
__global__ void pack_wf(const float* __restrict__ ggc, const float* __restrict__ w_ih,
                        unsigned short* __restrict__ Wfp) {
    int id = blockIdx.x * blockDim.x + threadIdx.x;
    if (id >= LAYERS * 4 * 24 * 64 * 8) return;
    int l = id / 49152;
    int rem = id % 49152;
    int j = rem & 7;
    int lane = (rem >> 3) & 63;
    int ctkt = rem >> 9;
    int ct = ctkt % 24;
    int kt = ctkt / 24;
    int k = kt * 32 + (lane >> 4) * 8 + j;
    int col = ct * 16 + (lane & 15);
    const float4* gr = (const float4*)(ggc + ((size_t)l * HH + k) * HH);
    const float4* wr = (const float4*)(w_ih + (size_t)col * HH);
    float acc = 0.0f;
#pragma unroll 4
    for (int q = 0; q < HH / 4; ++q) {
        float4 g = gr[q], w = wr[q];
        acc += g.x * w.x + g.y * w.y + g.z * w.z + g.w * w.w;
    }
    Wfp[id] = f2bf(acc);
}

// Fused layer: gather-aggregate (LDS) + GEMM(MFMA) + GRU epilogue.
// Block = 512 thr (8 waves) = 16 nodes; wave gathers 2 nodes, computes
// ct = {w, w+8, w+16} for gi and gh, epilogue fully in-wave.
// half=1 (layer 0): h rows have upper 64 channels == 0 -> gather reads only
// 128B/row (uint2/lane), hL upper zeroed, K-loop runs kt=0..1 only.
__global__ __launch_bounds__(512)
void layer_kernel(const unsigned short* __restrict__ hin,
                  unsigned short* __restrict__ hout,
                  const int* __restrict__ rowptr, const int* __restrict__ col,
                  const unsigned short* __restrict__ Wfp,
                  const unsigned short* __restrict__ whhp,
                  const float* __restrict__ b_ih, const float* __restrict__ b_hh,
                  int n, int half) {
    __shared__ unsigned short aggL[16 * LPAD_US];  // agg rows; reused for h_new in epilogue
    __shared__ unsigned short hL[16 * LPAD_US];    // staged hin rows
    int wave = threadIdx.x >> 6;   // 0..7
    int lane = threadIdx.x & 63;
    int quad = lane >> 4;
    int l15 = lane & 15;
    int lg = quad, l16 = l15;
    int M0 = blockIdx.x * 16;
    if (M0 >= n) return;
    const uint4* hin4 = (const uint4*)hin;
    const uint2* hin2 = (const uint2*)hin;

    // stage hin rows: threads 0-255 load 16 rows x 16 uint4 (upper half zero if half)
    if (threadIdx.x < 256) {
        int row = threadIdx.x >> 4;
        int q = threadIdx.x & 15;
        if (M0 + row < n) {
            uint4 v;
            if (half && q >= 8) v = make_uint4(0, 0, 0, 0);
            else v = hin4[(size_t)(M0 + row) * 16 + q];
            *(uint4*)(&hL[row * LPAD_US + q * 8]) = v;
            if (half && q >= 8) *(uint4*)(&aggL[row * LPAD_US + q * 8]) = make_uint4(0, 0, 0, 0);
        }
    }

    // prefetch rowptr[nb2..nb2+2] across lanes, broadcast via shfl
    int nb2 = M0 + wave * 2;
    int rp;
    {
        int idx = nb2 + lane;
        if (lane > 2 || idx > n) idx = n;
        rp = rowptr[idx];
    }

    // gather-aggregate: wave handles nodes [nb2, nb2+2)
    for (int i = 0; i < 2; ++i) {
        int node = nb2 + i;
        int r0 = __shfl(rp, i, 64);
        int r1 = __shfl(rp, i + 1, 64);
        if (node >= n) r1 = r0;
        if (half) {
            // 128B rows: lane l16 covers channels [l16*4, l16*4+4) via uint2
            float a[4], b[4];
#pragma unroll
            for (int k = 0; k < 4; ++k) { a[k] = 0.0f; b[k] = 0.0f; }
            int j = r0 + lg;
            for (; j + 4 < r1; j += 8) {
                int s0 = col[j], s1 = col[j + 4];
                uint2 v0 = hin2[(size_t)s0 * 32 + l16];
                uint2 v1 = hin2[(size_t)s1 * 32 + l16];
                a[0] += bflo(v0.x); a[1] += bfhi(v0.x);
                a[2] += bflo(v0.y); a[3] += bfhi(v0.y);
                b[0] += bflo(v1.x); b[1] += bfhi(v1.x);
                b[2] += bflo(v1.y); b[3] += bfhi(v1.y);
            }
            for (; j < r1; j += 4) {
                int s = col[j];
                uint2 v = hin2[(size_t)s * 32 + l16];
                a[0] += bflo(v.x); a[1] += bfhi(v.x);
                a[2] += bflo(v.y); a[3] += bfhi(v.y);
            }
#pragma unroll
            for (int k = 0; k < 4; ++k) {
                a[k] += b[k];
                a[k] += __shfl_xor(a[k], 32, 64);
                a[k] += __shfl_xor(a[k], 16, 64);
            }
            if (lg == 0 && node < n) {
                uint2 o;
                o.x = (unsigned)f2bf(a[0]) | ((unsigned)f2bf(a[1]) << 16);
                o.y = (unsigned)f2bf(a[2]) | ((unsigned)f2bf(a[3]) << 16);
                *(uint2*)(&aggL[(wave * 2 + i) * LPAD_US + l16 * 4]) = o;
            }
        } else {
            float a[8], b[8];
#pragma unroll
            for (int k = 0; k < 8; ++k) { a[k] = 0.0f; b[k] = 0.0f; }
            int j = r0 + lg;
            for (; j + 12 < r1; j += 16) {
                int s0 = col[j], s1 = col[j + 4], s2 = col[j + 8], s3 = col[j + 12];
                uint4 v0 = hin4[(size_t)s0 * 16 + l16];
                uint4 v1 = hin4[(size_t)s1 * 16 + l16];
                uint4 v2 = hin4[(size_t)s2 * 16 + l16];
                uint4 v3 = hin4[(size_t)s3 * 16 + l16];
                a[0] += bflo(v0.x); a[1] += bfhi(v0.x);
                a[2] += bflo(v0.y); a[3] += bfhi(v0.y);
                a[4] += bflo(v0.z); a[5] += bfhi(v0.z);
                a[6] += bflo(v0.w); a[7] += bfhi(v0.w);
                b[0] += bflo(v1.x); b[1] += bfhi(v1.x);
                b[2] += bflo(v1.y); b[3] += bfhi(v1.y);
                b[4] += bflo(v1.z); b[5] += bfhi(v1.z);
                b[6] += bflo(v1.w); b[7] += bfhi(v1.w);
                a[0] += bflo(v2.x); a[1] += bfhi(v2.x);
                a[2] += bflo(v2.y); a[3] += bfhi(v2.y);
                a[4] += bflo(v2.z); a[5] += bfhi(v2.z);
                a[6] += bflo(v2.w); a[7] += bfhi(v2.w);
                b[0] += bflo(v3.x); b[1] += bfhi(v3.x);
                b[2] += bflo(v3.y); b[3] += bfhi(v3.y);
                b[4] += bflo(v3.z); b[5] += bfhi(v3.z);
                b[6] += bflo(v3.w); b[7] += bfhi(v3.w);
            }
            for (; j + 4 < r1; j += 8) {
                int s0 = col[j], s1 = col[j + 4];
                uint4 v0 = hin4[(size_t)s0 * 16 + l16];
                uint4 v1 = hin4[(size_t)s1 * 16 + l16];
                a[0] += bflo(v0.x); a[1] += bfhi(v0.x);
                a[2] += bflo(v0.y); a[3] += bfhi(v0.y);
                a[4] += bflo(v0.z); a[5] += bfhi(v0.z);
                a[6] += bflo(v0.w); a[7] += bfhi(v0.w);
                b[0] += bflo(v1.x); b[1] += bfhi(v1.x);
                b[2] += bflo(v1.y); b[3] += bfhi(v1.y);
                b[4] += bflo(v1.z); b[5] += bfhi(v1.z);
                b[6] += bflo(v1.w); b[7] += bfhi(v1.w);
            }
            for (; j < r1; j += 4) {
                int s = col[j];
                uint4 v = hin4[(size_t)s * 16 + l16];
                a[0] += bflo(v.x); a[1] += bfhi(v.x);
                a[2] += bflo(v.y); a[3] += bfhi(v.y);
                a[4] += bflo(v.z); a[5] += bfhi(v.z);
                a[6] += bflo(v.w); a[7] += bfhi(v.w);
            }
#pragma unroll
            for (int k = 0; k < 8; ++k) {
                a[k] += b[k];
                a[k] += __shfl_xor(a[k], 32, 64);
                a[k] += __shfl_xor(a[k], 16, 64);
            }
            if (lg == 0 && node < n) {
                uint4 o;
                o.x = (unsigned)f2bf(a[0]) | ((unsigned)f2bf(a[1]) << 16);
                o.y = (unsigned)f2bf(a[2]) | ((unsigned)f2bf(a[3]) << 16);
                o.z = (unsigned)f2bf(a[4]) | ((unsigned)f2bf(a[5]) << 16);
                o.w = (unsigned)f2bf(a[6]) | ((unsigned)f2bf(a[7]) << 16);
                *(uint4*)(&aggL[(wave * 2 + i) * LPAD_US + l16 * 8]) = o;
            }
        }
    }

    __syncthreads();  // aggL + hL fully staged

    floatx4 acc_gi[3];
    floatx4 acc_gh[3];
#pragma unroll
    for (int g = 0; g < 3; ++g) {
        acc_gi[g] = (floatx4)0.0f;
        acc_gh[g] = (floatx4)0.0f;
    }

    int ktmax = half ? 2 : 4;
    for (int kt = 0; kt < ktmax; ++kt) {
        int kbase = kt * 32 + quad * 8;
        int lrow = l15 * LPAD_US + kbase;
        short8 a_a = *(const short8*)(&aggL[lrow]);
        short8 a_h = *(const short8*)(&hL[lrow]);
#pragma unroll
        for (int g = 0; g < 3; ++g) {
            int ct = g * 8 + wave;
            size_t boff = ((size_t)(kt * 24 + ct) * 64 + lane) * 8;
            short8 bi = *(const short8*)(Wfp + boff);
            short8 bh = *(const short8*)(whhp + boff);
            acc_gi[g] = __builtin_amdgcn_mfma_f32_16x16x32_bf16(a_a, bi, acc_gi[g], 0, 0, 0);
            acc_gh[g] = __builtin_amdgcn_mfma_f32_16x16x32_bf16(a_h, bh, acc_gh[g], 0, 0, 0);
        }
    }

    __syncthreads();  // K-loop reads of aggL done; safe to overwrite with h_new

    {
        int c = wave * 16 + l15;
        float bir = b_ih[c], biz = b_ih[128 + c], bin_ = b_ih[256 + c];
        float bhr = b_hh[c], bhz = b_hh[128 + c], bhn = b_hh[256 + c];
#pragma unroll
        for (int j = 0; j < 4; ++j) {
            int nl = quad * 4 + j;     // local node
            int lidx = nl * LPAD_US + c;
            float gir = acc_gi[0][j] + bir;
            float ghr = acc_gh[0][j] + bhr;
            float giz = acc_gi[1][j] + biz;
            float ghz = acc_gh[1][j] + bhz;
            float gin = acc_gi[2][j] + bin_;
            float ghn = acc_gh[2][j] + bhn;
            float rr = sigmf(gir + ghr);
            float zz = sigmf(giz + ghz);
            float nn = tanhfast(gin + rr * ghn);
            float hp = bfs(hL[lidx]);
            aggL[lidx] = f2bf((1.0f - zz) * nn + zz * hp);
        }
    }

    __syncthreads();

    // coalesced store of h_new to hout: threads 0-255 store 16 rows x 16 uint4
    if (threadIdx.x < 256) {
        int row = threadIdx.x >> 4;
        int q = threadIdx.x & 15;
        if (M0 + row < n) {
            uint4 v = *(const uint4*)(&aggL[row * LPAD_US + q * 8]);
            *(uint4*)(hout + (size_t)(M0 + row) * HH + q * 8) = v;
        }
    }
}

// Per-node mu/sigma from bf16 h. One wave per node, lane = 2 channels.
__global__ void readout_kernel(const unsigned int* __restrict__ h2, const float* __restrict__ w1,
                               const float* __restrict__ b1, const float* __restrict__ w2,
                               const float* __restrict__ b2,
                               float* __restrict__ out_mu, float* __restrict__ out_sg, int n) {
    int wave = (int)((blockIdx.x * blockDim.x + threadIdx.x) >> 6);
    int lane = threadIdx.x & 63;
    if (wave >= n) return;
    unsigned int u = h2[(size_t)wave * 64 + lane];
    float x0 = fmaxf(bflo(u), 0.0f);
    float x1 = fmaxf(bfhi(u), 0.0f);
    float2 wv1 = ((const float2*)w1)[lane];
    float2 wv2 = ((const float2*)w2)[lane];
    float a1 = x0 * wv1.x + x1 * wv1.y;
    float a2 = x0 * wv2.x + x1 * wv2.y;
#pragma unroll
    for (int off = 32; off > 0; off >>= 1) {
        a1 += __shfl_down(a1, off, 64);
        a2 += __shfl_down(a2, off, 64);
    }
    if (lane == 0) {
        float mu = a1 + b1[0];
        float x2 = a2 + b2[0];
        float sg = (x2 > 20.0f) ? x2 : __logf(1.0f + __expf(x2));
        out_mu[wave] = mu;
        out_sg[wave] = sg;
    }
}

__device__ __forceinline__ int lbound(const int* __restrict__ a, int n, int v) {
    int lo = 0, hi = n;
    while (lo < hi) {
        int m = (lo + hi) >> 1;
        if (a[m] < v) lo = m + 1; else hi = m;
    }
    return lo;
}

// One block per graph: block-reduce mu_all/sigma_all, apply correction. Zero atomics.
__global__ void seg_correct_kernel(const float* __restrict__ out_mu, const float* __restrict__ out_sg,
                                   const int* __restrict__ batch, float* __restrict__ out_muc, int n) {
    int g = blockIdx.x;
    int lo = lbound(batch, n, g);
    int hi = lbound(batch, n, g + 1);
    float smu = 0.0f, ssg = 0.0f;
    for (int i = lo + threadIdx.x; i < hi; i += blockDim.x) {
        smu += out_mu[i];
        ssg += out_sg[i];
    }
#pragma unroll
    for (int off = 32; off > 0; off >>= 1) {
        smu += __shfl_down(smu, off, 64);
        ssg += __shfl_down(ssg, off, 64);
    }
    __shared__ float pm[4], ps[4];
    int wave = threadIdx.x >> 6;
    int lane = threadIdx.x & 63;
    if (lane == 0) { pm[wave] = smu; ps[wave] = ssg; }
    __syncthreads();
    float tot_mu = pm[0] + pm[1] + pm[2] + pm[3];
    float tot_sg = ps[0] + ps[1] + ps[2] + ps[3];
    for (int i = lo + threadIdx.x; i < hi; i += blockDim.x) {
        out_muc[i] = out_mu[i] - tot_mu * (out_sg[i] / tot_sg);
    }
}

extern "C" void kernel_launch(void* const* d_in, const int* in_sizes, int n_in,
                              void* d_out, int out_size, void* d_ws, size_t ws_size,
                              hipStream_t stream) {
    const float* x      = (const float*)d_in[0];
    const int*   ei     = (const int*)d_in[1];
    const int*   batch  = (const int*)d_in[2];
    const float* lin0_w = (const float*)d_in[3];
    const float* ggc    = (const float*)d_in[4];
    const float* w_ih   = (const float*)d_in[5];
    const float* w_hh   = (const float*)d_in[6];
    const float* b_ih   = (const float*)d_in[7];
    const float* b_hh   = (const float*)d_in[8];
    const float* l1w    = (const float*)d_in[9];
    const float* l1b    = (const float*)d_in[10];
    const float* l2w    = (const float*)d_in[11];
    const float* l2b    = (const float*)d_in[12];

    int n = in_sizes[0] / FIN;   // 100000
    int e = in_sizes[1] / 2;     // 1600000
    const int* src = ei;
    const int* dstp = ei + e;

    float* out = (float*)d_out;
    float* out_muc = out;                              // [n]
    float* out_x1  = out + n;                          // [n*64]
    float* out_sg  = out + n + (size_t)n * EMB;        // [n]
    float* out_mu  = out_sg + n;                       // [n]

    // workspace layout (all 16B aligned)
    unsigned short* hbf0 = (unsigned short*)d_ws;                      // n*128 bf16
    unsigned short* hbf1 = hbf0 + (size_t)n * HH;                      // n*128 bf16
    unsigned short* Wfp  = hbf1 + (size_t)n * HH;                      // 4*49152 bf16
    unsigned short* whhp = Wfp + (size_t)LAYERS * 49152;               // 49152 bf16
    int*            deg      = (int*)(whhp + 49152 + 8);               // n
    int*            rowptr   = deg + n;                                // n+1
    int*            blocksum = rowptr + n + 1;                         // 64
    int*            blockoff = blocksum + 64;                          // 64
    int*            bucket_cnt = blockoff + 64;                        // MAXNB
    int*            col      = bucket_cnt + MAXNB;                     // e
    unsigned*       ebuf     = (unsigned*)hbf1;  // MAXNB*ECAP*4 = 16.8MB, aliases hbf1

    int nbuck = (n + SPAN - 1) >> SPANSHIFT;   // 196
    hipMemsetAsync(bucket_cnt, 0, MAXNB * sizeof(int), stream);

    int wave_blocks = (n * 64 + 255) / 256;
    lin0_kernel<<<wave_blocks, 256, 0, stream>>>(x, lin0_w, out_x1, hbf0, n);

    int eb = (e + 16383) / 16384;  // 98
    bucket_scatter_direct<<<eb, 1024, 0, stream>>>(src, dstp, bucket_cnt, ebuf, e);
    deg_from_buckets<<<nbuck, 256, 0, stream>>>(ebuf, bucket_cnt, deg, n);

    int nb = (n + SCAN_CHUNK) / SCAN_CHUNK;  // covers idx==n too
    scan_partial<<<nb, 256, 0, stream>>>(deg, blocksum, n);
    scan_blocksums<<<1, 64, 0, stream>>>(blocksum, blockoff, nb);
    scan_final<<<nb, 256, 0, stream>>>(deg, blockoff, rowptr, n);

    place_kernel<<<nbuck, 256, 0, stream>>>(ebuf, bucket_cnt, rowptr, col, n);

    pack_whh<<<(49152 + 255) / 256, 256, 0, stream>>>(w_hh, whhp);
    pack_wf<<<(LAYERS * 49152 + 255) / 256, 256, 0, stream>>>(ggc, w_ih, Wfp);

    int gru_blocks = (n + 15) / 16;  // 6250
    unsigned short* hin = hbf0;
    unsigned short* hout = hbf1;
    for (int l = 0; l < LAYERS; ++l) {
        layer_kernel<<<gru_blocks, 512, 0, stream>>>(hin, hout, rowptr, col,
                                                     Wfp + (size_t)l * 49152, whhp,
                                                     b_ih, b_hh, n, (l == 0) ? 1 : 0);
        unsigned short* t = hin; hin = hout; hout = t;
    }
    // LAYERS=4 (even) -> final state in hbf0 (= hin after loop)

    readout_kernel<<<wave_blocks, 256, 0, stream>>>((const unsigned int*)hin, l1w, l1b, l2w, l2b,
                                                    out_mu, out_sg, n);
    seg_correct_kernel<<<GG, 256, 0, stream>>>(out_mu, out_sg, batch, out_muc, n);
}

// Round 14
// 627.188 us; speedup vs baseline: 1.0859x; 1.0859x over previous
//
#include <hip/hip_runtime.h>
#include <math.h>

#define NN 100000
#define FIN 27
#define EMB 64
#define HH 128
#define LAYERS 4
#define GG 512
#define SCAN_CHUNK 2048   // 256 threads x 8 elements
#define SPAN 512          // nodes per bucket
#define SPANSHIFT 9
#define MAXNB 256
#define ECAP 16384        // per-bucket edge slab capacity (mean ~8163)
#define LPAD_US 136       // LDS row stride in ushorts: 272B, 16B-aligned rows

typedef __attribute__((ext_vector_type(8))) short short8;
typedef __attribute__((ext_vector_type(4))) float floatx4;

__device__ __forceinline__ float sigmf(float x) { return 1.0f / (1.0f + __expf(-x)); }
__device__ __forceinline__ float tanhfast(float x) { return 1.0f - 2.0f / (__expf(2.0f * x) + 1.0f); }

__device__ __forceinline__ unsigned short f2bf(float f) {
    unsigned int u = __float_as_uint(f);
    u += 0x7FFFu + ((u >> 16) & 1u);
    return (unsigned short)(u >> 16);
}

__device__ __forceinline__ float bflo(unsigned int v) { return __uint_as_float(v << 16); }
__device__ __forceinline__ float bfhi(unsigned int v) { return __uint_as_float(v & 0xFFFF0000u); }
__device__ __forceinline__ float bfs(unsigned short v) { return __uint_as_float(((unsigned)v) << 16); }

// x1 = sigmoid(x @ lin0_w) (fp32, exact output); h = pad(x1) to 128, bf16 only.
__global__ void lin0_kernel(const float* __restrict__ x, const float* __restrict__ w,
                            float* __restrict__ x1_out, unsigned short* __restrict__ hbf, int n) {
    int wave = (int)((blockIdx.x * blockDim.x + threadIdx.x) >> 6);
    int lane = threadIdx.x & 63;
    if (wave >= n) return;
    const float* xr = x + (size_t)wave * FIN;
    float acc = 0.0f;
#pragma unroll
    for (int k = 0; k < FIN; ++k) acc += xr[k] * w[k * EMB + lane];
    float v = 1.0f / (1.0f + expf(-acc));
    x1_out[(size_t)wave * EMB + lane] = v;
    size_t base = (size_t)wave * HH;
    hbf[base + lane] = f2bf(v);
    hbf[base + 64 + lane] = 0;
}

// Direct-reservation bucketed scatter: one pass over edges. Per-block LDS hist,
// one global atomic per (block,bucket), packed (dst_local<<17)|src into slab b*ECAP.
__global__ void bucket_scatter_direct(const int* __restrict__ src, const int* __restrict__ dst,
                                      int* __restrict__ bucket_cnt, unsigned* __restrict__ ebuf,
                                      int e) {
    __shared__ int lh[MAXNB];
    __shared__ int gb[MAXNB];
    int t = threadIdx.x;  // 1024
    for (int i = t; i < MAXNB; i += 1024) lh[i] = 0;
    __syncthreads();
    int base = blockIdx.x * 16384;
    int lidx[16], sv[16], dv[16];
#pragma unroll
    for (int i = 0; i < 16; ++i) {
        int eid = base + i * 1024 + t;
        if (eid < e) {
            sv[i] = src[eid];
            dv[i] = dst[eid];
            lidx[i] = atomicAdd(&lh[dv[i] >> SPANSHIFT], 1);
        } else lidx[i] = -1;
    }
    __syncthreads();
    for (int i = t; i < MAXNB; i += 1024) {
        int c = lh[i];
        gb[i] = c ? atomicAdd(&bucket_cnt[i], c) : 0;
    }
    __syncthreads();
#pragma unroll
    for (int i = 0; i < 16; ++i) {
        if (lidx[i] >= 0) {
            int b = dv[i] >> SPANSHIFT;
            int pos = gb[b] + lidx[i];
            if (pos < ECAP) {
                unsigned dl = (unsigned)(dv[i] - (b << SPANSHIFT));
                ebuf[(size_t)b * ECAP + pos] = (dl << 17) | (unsigned)sv[i];
            }
        }
    }
}

// Per-node degree via per-bucket LDS histogram.
__global__ void deg_from_buckets(const unsigned* __restrict__ ebuf, const int* __restrict__ bucket_cnt,
                                 int* __restrict__ deg, int n) {
    __shared__ int ld[SPAN];
    int b = blockIdx.x, t = threadIdx.x;  // 256
    ld[t] = 0; ld[t + 256] = 0;
    __syncthreads();
    int cnt = bucket_cnt[b];
    if (cnt > ECAP) cnt = ECAP;
    size_t base = (size_t)b * ECAP;
    int nodebase = b << SPANSHIFT;
    for (int j = t; j < cnt; j += 256)
        atomicAdd(&ld[ebuf[base + j] >> 17], 1);
    __syncthreads();
    int i0 = nodebase + t, i1 = nodebase + 256 + t;
    if (i0 < n) deg[i0] = ld[t];
    if (i1 < n) deg[i1] = ld[t + 256];
}

// ---- multi-block exclusive scan of deg -> rowptr ----
__global__ void scan_partial(const int* __restrict__ deg, int* __restrict__ blocksum, int n) {
    int b = blockIdx.x, t = threadIdx.x;
    int base = b * SCAN_CHUNK + t * 8;
    int s = 0;
#pragma unroll
    for (int i = 0; i < 8; ++i) {
        int idx = base + i;
        if (idx < n) s += deg[idx];
    }
#pragma unroll
    for (int off = 32; off > 0; off >>= 1) s += __shfl_down(s, off, 64);
    __shared__ int ws[4];
    if ((t & 63) == 0) ws[t >> 6] = s;
    __syncthreads();
    if (t == 0) blocksum[b] = ws[0] + ws[1] + ws[2] + ws[3];
}

__global__ void scan_blocksums(const int* __restrict__ blocksum, int* __restrict__ blockoff, int nb) {
    int t = threadIdx.x;
    int own = (t < nb) ? blocksum[t] : 0;
    int v = own;
    for (int off = 1; off < 64; off <<= 1) {
        int u = __shfl_up(v, off, 64);
        if (t >= off) v += u;
    }
    if (t < nb) blockoff[t] = v - own;
}

__global__ void scan_final(const int* __restrict__ deg, const int* __restrict__ blockoff,
                           int* __restrict__ rowptr, int n) {
    int b = blockIdx.x, t = threadIdx.x;
    int base = b * SCAN_CHUNK + t * 8;
    int v[8];
    int s = 0;
#pragma unroll
    for (int i = 0; i < 8; ++i) {
        int idx = base + i;
        v[i] = (idx < n) ? deg[idx] : 0;
        s += v[i];
    }
    __shared__ int ts[256];
    ts[t] = s;
    __syncthreads();
    for (int off = 1; off < 256; off <<= 1) {
        int u = (t >= off) ? ts[t - off] : 0;
        __syncthreads();
        ts[t] += u;
        __syncthreads();
    }
    int run = blockoff[b] + ((t == 0) ? 0 : ts[t - 1]);
#pragma unroll
    for (int i = 0; i < 8; ++i) {
        int idx = base + i;
        if (idx < n) {
            rowptr[idx] = run;
            run += v[i];
        } else if (idx == n) {
            rowptr[n] = run;
        }
    }
}

// Place edges into CSR col with LDS cursors; writes confined to ~32KB/bucket.
__global__ void place_kernel(const unsigned* __restrict__ ebuf, const int* __restrict__ bucket_cnt,
                             const int* __restrict__ rowptr, int* __restrict__ col, int n) {
    __shared__ int cur[SPAN];
    int b = blockIdx.x, t = threadIdx.x;  // 256
    int nodebase = b << SPANSHIFT;
    int i0 = nodebase + t, i1 = nodebase + 256 + t;
    cur[t] = (i0 < n) ? rowptr[i0] : 0;
    cur[t + 256] = (i1 < n) ? rowptr[i1] : 0;
    __syncthreads();
    int cnt = bucket_cnt[b];
    if (cnt > ECAP) cnt = ECAP;
    size_t base = (size_t)b * ECAP;
    for (int j = t; j < cnt; j += 256) {
        unsigned ed = ebuf[base + j];
        int pos = atomicAdd(&cur[ed >> 17], 1);
        col[pos] = (int)(ed & 0x1FFFFu);
    }
}

// Pack whh^T into MFMA B-fragment order.
__global__ void pack_whh(const float* __restrict__ w_hh, unsigned short* __restrict__ whhp) {
    int id = blockIdx.x * blockDim.x + threadIdx.x;
    if (id >= 4 * 24 * 64 * 8) return;
    int j = id & 7;
    int lane = (id >> 3) & 63;
    int ctkt = id >> 9;
    int ct = ctkt % 24;
    int kt = ctkt / 24;
    int k = kt * 32 + (lane >> 4) * 8 + j;
    int col = ct * 16 + (lane & 15);
    whhp[id] = f2bf(w_hh[col * HH + k]);
}

// Wf[l] = ggc[l] @ w_ih^T, packed in MFMA B-fragment order (bf16).
__global__ void pack_wf(const float* __restrict__ ggc, const float* __restrict__ w_ih,
                        unsigned short* __restrict__ Wfp) {
    int id = blockIdx.x * blockDim.x + threadIdx.x;
    if (id >= LAYERS * 4 * 24 * 64 * 8) return;
    int l = id / 49152;
    int rem = id % 49152;
    int j = rem & 7;
    int lane = (rem >> 3) & 63;
    int ctkt = rem >> 9;
    int ct = ctkt % 24;
    int kt = ctkt / 24;
    int k = kt * 32 + (lane >> 4) * 8 + j;
    int col = ct * 16 + (lane & 15);
    const float4* gr = (const float4*)(ggc + ((size_t)l * HH + k) * HH);
    const float4* wr = (const float4*)(w_ih + (size_t)col * HH);
    float acc = 0.0f;
#pragma unroll 4
    for (int q = 0; q < HH / 4; ++q) {
        float4 g = gr[q], w = wr[q];
        acc += g.x * w.x + g.y * w.y + g.z * w.z + g.w * w.w;
    }
    Wfp[id] = f2bf(acc);
}

// Fused layer: gather-aggregate (LDS) + GEMM(MFMA) + GRU epilogue.
// Block = 512 thr (8 waves) = 16 nodes; wave gathers 2 nodes, computes
// ct = {w, w+8, w+16} for gi and gh, epilogue fully in-wave.
// HALF=1 (layer 0, compile-time): h rows have upper 64 channels == 0 ->
// gather reads only 128B/row (uint2/lane), hL upper zeroed, K-loop kt=0..1.
template <int HALF>
__global__ __launch_bounds__(512)
void layer_kernel(const unsigned short* __restrict__ hin,
                  unsigned short* __restrict__ hout,
                  const int* __restrict__ rowptr, const int* __restrict__ col,
                  const unsigned short* __restrict__ Wfp,
                  const unsigned short* __restrict__ whhp,
                  const float* __restrict__ b_ih, const float* __restrict__ b_hh,
                  int n) {
    __shared__ unsigned short aggL[16 * LPAD_US];  // agg rows; reused for h_new in epilogue
    __shared__ unsigned short hL[16 * LPAD_US];    // staged hin rows
    int wave = threadIdx.x >> 6;   // 0..7
    int lane = threadIdx.x & 63;
    int quad = lane >> 4;
    int l15 = lane & 15;
    int lg = quad, l16 = l15;
    int M0 = blockIdx.x * 16;
    if (M0 >= n) return;
    const uint4* hin4 = (const uint4*)hin;
    const uint2* hin2 = (const uint2*)hin;

    // stage hin rows: threads 0-255 load 16 rows x 16 uint4 (upper half zero if HALF)
    if (threadIdx.x < 256) {
        int row = threadIdx.x >> 4;
        int q = threadIdx.x & 15;
        if (M0 + row < n) {
            uint4 v;
            if (HALF && q >= 8) v = make_uint4(0, 0, 0, 0);
            else v = hin4[(size_t)(M0 + row) * 16 + q];
            *(uint4*)(&hL[row * LPAD_US + q * 8]) = v;
            if (HALF && q >= 8) *(uint4*)(&aggL[row * LPAD_US + q * 8]) = make_uint4(0, 0, 0, 0);
        }
    }

    // prefetch rowptr[nb2..nb2+2] across lanes, broadcast via shfl
    int nb2 = M0 + wave * 2;
    int rp;
    {
        int idx = nb2 + lane;
        if (lane > 2 || idx > n) idx = n;
        rp = rowptr[idx];
    }

    // gather-aggregate: wave handles nodes [nb2, nb2+2)
    for (int i = 0; i < 2; ++i) {
        int node = nb2 + i;
        int r0 = __shfl(rp, i, 64);
        int r1 = __shfl(rp, i + 1, 64);
        if (node >= n) r1 = r0;
        if (HALF) {
            // 128B rows: lane l16 covers channels [l16*4, l16*4+4) via uint2
            float a[4], b[4];
#pragma unroll
            for (int k = 0; k < 4; ++k) { a[k] = 0.0f; b[k] = 0.0f; }
            int j = r0 + lg;
            for (; j + 4 < r1; j += 8) {
                int s0 = col[j], s1 = col[j + 4];
                uint2 v0 = hin2[(size_t)s0 * 32 + l16];
                uint2 v1 = hin2[(size_t)s1 * 32 + l16];
                a[0] += bflo(v0.x); a[1] += bfhi(v0.x);
                a[2] += bflo(v0.y); a[3] += bfhi(v0.y);
                b[0] += bflo(v1.x); b[1] += bfhi(v1.x);
                b[2] += bflo(v1.y); b[3] += bfhi(v1.y);
            }
            for (; j < r1; j += 4) {
                int s = col[j];
                uint2 v = hin2[(size_t)s * 32 + l16];
                a[0] += bflo(v.x); a[1] += bfhi(v.x);
                a[2] += bflo(v.y); a[3] += bfhi(v.y);
            }
#pragma unroll
            for (int k = 0; k < 4; ++k) {
                a[k] += b[k];
                a[k] += __shfl_xor(a[k], 32, 64);
                a[k] += __shfl_xor(a[k], 16, 64);
            }
            if (lg == 0 && node < n) {
                uint2 o;
                o.x = (unsigned)f2bf(a[0]) | ((unsigned)f2bf(a[1]) << 16);
                o.y = (unsigned)f2bf(a[2]) | ((unsigned)f2bf(a[3]) << 16);
                *(uint2*)(&aggL[(wave * 2 + i) * LPAD_US + l16 * 4]) = o;
            }
        } else {
            float a[8], b[8];
#pragma unroll
            for (int k = 0; k < 8; ++k) { a[k] = 0.0f; b[k] = 0.0f; }
            int j = r0 + lg;
            for (; j + 12 < r1; j += 16) {
                int s0 = col[j], s1 = col[j + 4], s2 = col[j + 8], s3 = col[j + 12];
                uint4 v0 = hin4[(size_t)s0 * 16 + l16];
                uint4 v1 = hin4[(size_t)s1 * 16 + l16];
                uint4 v2 = hin4[(size_t)s2 * 16 + l16];
                uint4 v3 = hin4[(size_t)s3 * 16 + l16];
                a[0] += bflo(v0.x); a[1] += bfhi(v0.x);
                a[2] += bflo(v0.y); a[3] += bfhi(v0.y);
                a[4] += bflo(v0.z); a[5] += bfhi(v0.z);
                a[6] += bflo(v0.w); a[7] += bfhi(v0.w);
                b[0] += bflo(v1.x); b[1] += bfhi(v1.x);
                b[2] += bflo(v1.y); b[3] += bfhi(v1.y);
                b[4] += bflo(v1.z); b[5] += bfhi(v1.z);
                b[6] += bflo(v1.w); b[7] += bfhi(v1.w);
                a[0] += bflo(v2.x); a[1] += bfhi(v2.x);
                a[2] += bflo(v2.y); a[3] += bfhi(v2.y);
                a[4] += bflo(v2.z); a[5] += bfhi(v2.z);
                a[6] += bflo(v2.w); a[7] += bfhi(v2.w);
                b[0] += bflo(v3.x); b[1] += bfhi(v3.x);
                b[2] += bflo(v3.y); b[3] += bfhi(v3.y);
                b[4] += bflo(v3.z); b[5] += bfhi(v3.z);
                b[6] += bflo(v3.w); b[7] += bfhi(v3.w);
            }
            for (; j + 4 < r1; j += 8) {
                int s0 = col[j], s1 = col[j + 4];
                uint4 v0 = hin4[(size_t)s0 * 16 + l16];
                uint4 v1 = hin4[(size_t)s1 * 16 + l16];
                a[0] += bflo(v0.x); a[1] += bfhi(v0.x);
                a[2] += bflo(v0.y); a[3] += bfhi(v0.y);
                a[4] += bflo(v0.z); a[5] += bfhi(v0.z);
                a[6] += bflo(v0.w); a[7] += bfhi(v0.w);
                b[0] += bflo(v1.x); b[1] += bfhi(v1.x);
                b[2] += bflo(v1.y); b[3] += bfhi(v1.y);
                b[4] += bflo(v1.z); b[5] += bfhi(v1.z);
                b[6] += bflo(v1.w); b[7] += bfhi(v1.w);
            }
            for (; j < r1; j += 4) {
                int s = col[j];
                uint4 v = hin4[(size_t)s * 16 + l16];
                a[0] += bflo(v.x); a[1] += bfhi(v.x);
                a[2] += bflo(v.y); a[3] += bfhi(v.y);
                a[4] += bflo(v.z); a[5] += bfhi(v.z);
                a[6] += bflo(v.w); a[7] += bfhi(v.w);
            }
#pragma unroll
            for (int k = 0; k < 8; ++k) {
                a[k] += b[k];
                a[k] += __shfl_xor(a[k], 32, 64);
                a[k] += __shfl_xor(a[k], 16, 64);
            }
            if (lg == 0 && node < n) {
                uint4 o;
                o.x = (unsigned)f2bf(a[0]) | ((unsigned)f2bf(a[1]) << 16);
                o.y = (unsigned)f2bf(a[2]) | ((unsigned)f2bf(a[3]) << 16);
                o.z = (unsigned)f2bf(a[4]) | ((unsigned)f2bf(a[5]) << 16);
                o.w = (unsigned)f2bf(a[6]) | ((unsigned)f2bf(a[7]) << 16);
                *(uint4*)(&aggL[(wave * 2 + i) * LPAD_US + l16 * 8]) = o;
            }
        }
    }

    __syncthreads();  // aggL + hL fully staged

    floatx4 acc_gi[3];
    floatx4 acc_gh[3];
#pragma unroll
    for (int g = 0; g < 3; ++g) {
        acc_gi[g] = (floatx4)0.0f;
        acc_gh[g] = (floatx4)0.0f;
    }

    const int KTMAX = HALF ? 2 : 4;
#pragma unroll
    for (int kt = 0; kt < KTMAX; ++kt) {
        int kbase = kt * 32 + quad * 8;
        int lrow = l15 * LPAD_US + kbase;
        short8 a_a = *(const short8*)(&aggL[lrow]);
        short8 a_h = *(const short8*)(&hL[lrow]);
#pragma unroll
        for (int g = 0; g < 3; ++g) {
            int ct = g * 8 + wave;
            size_t boff = ((size_t)(kt * 24 + ct) * 64 + lane) * 8;
            short8 bi = *(const short8*)(Wfp + boff);
            short8 bh = *(const short8*)(whhp + boff);
            acc_gi[g] = __builtin_amdgcn_mfma_f32_16x16x32_bf16(a_a, bi, acc_gi[g], 0, 0, 0);
            acc_gh[g] = __builtin_amdgcn_mfma_f32_16x16x32_bf16(a_h, bh, acc_gh[g], 0, 0, 0);
        }
    }

    __syncthreads();  // K-loop reads of aggL done; safe to overwrite with h_new

    {
        int c = wave * 16 + l15;
        float bir = b_ih[c], biz = b_ih[128 + c], bin_ = b_ih[256 + c];
        float bhr = b_hh[c], bhz = b_hh[128 + c], bhn = b_hh[256 + c];
#pragma unroll
        for (int j = 0; j < 4; ++j) {
            int nl = quad * 4 + j;     // local node
            int lidx = nl * LPAD_US + c;
            float gir = acc_gi[0][j] + bir;
            float ghr = acc_gh[0][j] + bhr;
            float giz = acc_gi[1][j] + biz;
            float ghz = acc_gh[1][j] + bhz;
            float gin = acc_gi[2][j] + bin_;
            float ghn = acc_gh[2][j] + bhn;
            float rr = sigmf(gir + ghr);
            float zz = sigmf(giz + ghz);
            float nn = tanhfast(gin + rr * ghn);
            float hp = bfs(hL[lidx]);
            aggL[lidx] = f2bf((1.0f - zz) * nn + zz * hp);
        }
    }

    __syncthreads();

    // coalesced store of h_new to hout: threads 0-255 store 16 rows x 16 uint4
    if (threadIdx.x < 256) {
        int row = threadIdx.x >> 4;
        int q = threadIdx.x & 15;
        if (M0 + row < n) {
            uint4 v = *(const uint4*)(&aggL[row * LPAD_US + q * 8]);
            *(uint4*)(hout + (size_t)(M0 + row) * HH + q * 8) = v;
        }
    }
}

// Per-node mu/sigma from bf16 h. One wave per node, lane = 2 channels.
__global__ void readout_kernel(const unsigned int* __restrict__ h2, const float* __restrict__ w1,
                               const float* __restrict__ b1, const float* __restrict__ w2,
                               const float* __restrict__ b2,
                               float* __restrict__ out_mu, float* __restrict__ out_sg, int n) {
    int wave = (int)((blockIdx.x * blockDim.x + threadIdx.x) >> 6);
    int lane = threadIdx.x & 63;
    if (wave >= n) return;
    unsigned int u = h2[(size_t)wave * 64 + lane];
    float x0 = fmaxf(bflo(u), 0.0f);
    float x1 = fmaxf(bfhi(u), 0.0f);
    float2 wv1 = ((const float2*)w1)[lane];
    float2 wv2 = ((const float2*)w2)[lane];
    float a1 = x0 * wv1.x + x1 * wv1.y;
    float a2 = x0 * wv2.x + x1 * wv2.y;
#pragma unroll
    for (int off = 32; off > 0; off >>= 1) {
        a1 += __shfl_down(a1, off, 64);
        a2 += __shfl_down(a2, off, 64);
    }
    if (lane == 0) {
        float mu = a1 + b1[0];
        float x2 = a2 + b2[0];
        float sg = (x2 > 20.0f) ? x2 : __logf(1.0f + __expf(x2));
        out_mu[wave] = mu;
        out_sg[wave] = sg;
    }
}

__device__ __forceinline__ int lbound(const int* __restrict__ a, int n, int v) {
    int lo = 0, hi = n;
    while (lo < hi) {
        int m = (lo + hi) >> 1;
        if (a[m] < v) lo = m + 1; else hi = m;
    }
    return lo;
}

// One block per graph: block-reduce mu_all/sigma_all, apply correction. Zero atomics.
__global__ void seg_correct_kernel(const float* __restrict__ out_mu, const float* __restrict__ out_sg,
                                   const int* __restrict__ batch, float* __restrict__ out_muc, int n) {
    int g = blockIdx.x;
    int lo = lbound(batch, n, g);
    int hi = lbound(batch, n, g + 1);
    float smu = 0.0f, ssg = 0.0f;
    for (int i = lo + threadIdx.x; i < hi; i += blockDim.x) {
        smu += out_mu[i];
        ssg += out_sg[i];
    }
#pragma unroll
    for (int off = 32; off > 0; off >>= 1) {
        smu += __shfl_down(smu, off, 64);
        ssg += __shfl_down(ssg, off, 64);
    }
    __shared__ float pm[4], ps[4];
    int wave = threadIdx.x >> 6;
    int lane = threadIdx.x & 63;
    if (lane == 0) { pm[wave] = smu; ps[wave] = ssg; }
    __syncthreads();
    float tot_mu = pm[0] + pm[1] + pm[2] + pm[3];
    float tot_sg = ps[0] + ps[1] + ps[2] + ps[3];
    for (int i = lo + threadIdx.x; i < hi; i += blockDim.x) {
        out_muc[i] = out_mu[i] - tot_mu * (out_sg[i] / tot_sg);
    }
}

extern "C" void kernel_launch(void* const* d_in, const int* in_sizes, int n_in,
                              void* d_out, int out_size, void* d_ws, size_t ws_size,
                              hipStream_t stream) {
    const float* x      = (const float*)d_in[0];
    const int*   ei     = (const int*)d_in[1];
    const int*   batch  = (const int*)d_in[2];
    const float* lin0_w = (const float*)d_in[3];
    const float* ggc    = (const float*)d_in[4];
    const float* w_ih   = (const float*)d_in[5];
    const float* w_hh   = (const float*)d_in[6];
    const float* b_ih   = (const float*)d_in[7];
    const float* b_hh   = (const float*)d_in[8];
    const float* l1w    = (const float*)d_in[9];
    const float* l1b    = (const float*)d_in[10];
    const float* l2w    = (const float*)d_in[11];
    const float* l2b    = (const float*)d_in[12];

    int n = in_sizes[0] / FIN;   // 100000
    int e = in_sizes[1] / 2;     // 1600000
    const int* src = ei;
    const int* dstp = ei + e;

    float* out = (float*)d_out;
    float* out_muc = out;                              // [n]
    float* out_x1  = out + n;                          // [n*64]
    float* out_sg  = out + n + (size_t)n * EMB;        // [n]
    float* out_mu  = out_sg + n;                       // [n]

    // workspace layout (all 16B aligned)
    unsigned short* hbf0 = (unsigned short*)d_ws;                      // n*128 bf16
    unsigned short* hbf1 = hbf0 + (size_t)n * HH;                      // n*128 bf16
    unsigned short* Wfp  = hbf1 + (size_t)n * HH;                      // 4*49152 bf16
    unsigned short* whhp = Wfp + (size_t)LAYERS * 49152;               // 49152 bf16
    int*            deg      = (int*)(whhp + 49152 + 8);               // n
    int*            rowptr   = deg + n;                                // n+1
    int*            blocksum = rowptr + n + 1;                         // 64
    int*            blockoff = blocksum + 64;                          // 64
    int*            bucket_cnt = blockoff + 64;                        // MAXNB
    int*            col      = bucket_cnt + MAXNB;                     // e
    unsigned*       ebuf     = (unsigned*)hbf1;  // MAXNB*ECAP*4 = 16.8MB, aliases hbf1

    int nbuck = (n + SPAN - 1) >> SPANSHIFT;   // 196
    hipMemsetAsync(bucket_cnt, 0, MAXNB * sizeof(int), stream);

    int wave_blocks = (n * 64 + 255) / 256;
    lin0_kernel<<<wave_blocks, 256, 0, stream>>>(x, lin0_w, out_x1, hbf0, n);

    int eb = (e + 16383) / 16384;  // 98
    bucket_scatter_direct<<<eb, 1024, 0, stream>>>(src, dstp, bucket_cnt, ebuf, e);
    deg_from_buckets<<<nbuck, 256, 0, stream>>>(ebuf, bucket_cnt, deg, n);

    int nb = (n + SCAN_CHUNK) / SCAN_CHUNK;  // covers idx==n too
    scan_partial<<<nb, 256, 0, stream>>>(deg, blocksum, n);
    scan_blocksums<<<1, 64, 0, stream>>>(blocksum, blockoff, nb);
    scan_final<<<nb, 256, 0, stream>>>(deg, blockoff, rowptr, n);

    place_kernel<<<nbuck, 256, 0, stream>>>(ebuf, bucket_cnt, rowptr, col, n);

    pack_whh<<<(49152 + 255) / 256, 256, 0, stream>>>(w_hh, whhp);
    pack_wf<<<(LAYERS * 49152 + 255) / 256, 256, 0, stream>>>(ggc, w_ih, Wfp);

    int gru_blocks = (n + 15) / 16;  // 6250
    unsigned short* hin = hbf0;
    unsigned short* hout = hbf1;
    for (int l = 0; l < LAYERS; ++l) {
        if (l == 0) {
            layer_kernel<1><<<gru_blocks, 512, 0, stream>>>(hin, hout, rowptr, col,
                                                            Wfp, whhp, b_ih, b_hh, n);
        } else {
            layer_kernel<0><<<gru_blocks, 512, 0, stream>>>(hin, hout, rowptr, col,
                                                            Wfp + (size_t)l * 49152, whhp,
                                                            b_ih, b_hh, n);
        }
        unsigned short* t = hin; hin = hout; hout = t;
    }
    // LAYERS=4 (even) -> final state in hbf0 (= hin after loop)

    readout_kernel<<<wave_blocks, 256, 0, stream>>>((const unsigned int*)hin, l1w, l1b, l2w, l2b,
                                                    out_mu, out_sg, n);
    seg_correct_kernel<<<GG, 256, 0, stream>>>(out_mu, out_sg, batch, out_muc, n);
}